// Round 4
// baseline (356.749 us; speedup 1.0000x reference)
//
#include <hip/hip_runtime.h>
#include <math.h>

#define BK 10
#define KNODES 1024   // nodes per bucket
#define MAXNB 128     // max buckets (N <= 131072, src fits 17 bits)

typedef __attribute__((ext_vector_type(8))) short bf16x8;
typedef __attribute__((ext_vector_type(4))) float f32x4;

// ---- bf16 helpers ----------------------------------------------------------
__device__ __forceinline__ float bf2f(unsigned short u) {
  return __uint_as_float(((unsigned int)u) << 16);
}
__device__ __forceinline__ unsigned short f2bf(float f) {
  unsigned int i = __float_as_uint(f);
  unsigned int r = i + 0x7FFFu + ((i >> 16) & 1u);   // round-to-nearest-even
  return (unsigned short)(r >> 16);
}

// ---------------- prep: bpos init + W1/W2 frags + va + sentinels (1 launch) --
__global__ __launch_bounds__(256) void prep_kernel(
    const float* __restrict__ W1, const float* __restrict__ W2,
    const float* __restrict__ a2s, const float* __restrict__ a2d,
    unsigned short* __restrict__ whi, unsigned short* __restrict__ wlo,
    unsigned short* __restrict__ w2hi, unsigned short* __restrict__ w2lo,
    float* __restrict__ vas, float* __restrict__ vad,
    unsigned short* __restrict__ h1b, unsigned short* __restrict__ h2b,
    float* __restrict__ s1s, float* __restrict__ s2s,
    int* __restrict__ bpos, int capP, int NN) {
  const int blk = blockIdx.x, t = threadIdx.x;
  if (blk == 0 && t < MAXNB) bpos[t] = t * capP;
  if (blk < 32) {
    if (t < 64) {
      // W1 -> MFMA B-frag layout, hi/lo bf16 split. tile b=kt*4+ct
      int b = blk, lane = t;
      int kt = b >> 2, ct = b & 3;
      int n = lane & 15, g = lane >> 4;
      unsigned short hb[8], lb[8];
#pragma unroll
      for (int j = 0; j < 8; ++j) {
        int k = kt * 32 + g * 8 + j;
        float wv = W1[k * 64 + ct * 16 + n];
        unsigned short hi = f2bf(wv);
        float rem = wv - bf2f(hi);
        hb[j] = hi;
        lb[j] = f2bf(rem);
      }
      size_t base = ((size_t)b * 64 + lane) * 8;
      *(ushort4*)(whi + base)     = make_ushort4(hb[0], hb[1], hb[2], hb[3]);
      *(ushort4*)(whi + base + 4) = make_ushort4(hb[4], hb[5], hb[6], hb[7]);
      *(ushort4*)(wlo + base)     = make_ushort4(lb[0], lb[1], lb[2], lb[3]);
      *(ushort4*)(wlo + base + 4) = make_ushort4(lb[4], lb[5], lb[6], lb[7]);
    }
  } else if (blk == 32) {
    if (t < 64) {
      float s = 0.f, d = 0.f;
      for (int c = 0; c < 40; ++c) {
        float w = W2[t * 40 + c];
        s += w * a2s[c];
        d += w * a2d[c];
      }
      vas[t] = s;
      vad[t] = d;
    }
  } else if (blk == 33) {
    if (t < 64) {
      h1b[(size_t)NN * 64 + t] = 0;
      if (t < 40) h2b[(size_t)NN * 40 + t] = 0;
      if (t < 8)  s1s[(size_t)NN * 8 + t] = -1e30f;
      if (t == 0) s2s[NN] = -1e30f;
    }
  } else if (blk >= 34 && blk < 40) {
    if (t < 64) {
      // W2 -> MFMA B-frag layout, hi/lo bf16 split. tile b = kt*3+ct (kt<2, ct<3)
      int b = blk - 34;
      int kt = b / 3, ct = b % 3;
      int n = t & 15, g = t >> 4;
      unsigned short hb[8], lb[8];
#pragma unroll
      for (int j = 0; j < 8; ++j) {
        int k = kt * 32 + g * 8 + j;          // < 64
        int c = ct * 16 + n;
        float wv = (c < 40) ? W2[k * 40 + c] : 0.f;
        unsigned short hi = f2bf(wv);
        float rem = wv - bf2f(hi);
        hb[j] = hi;
        lb[j] = f2bf(rem);
      }
      size_t base = ((size_t)b * 64 + t) * 8;
      *(ushort4*)(w2hi + base)     = make_ushort4(hb[0], hb[1], hb[2], hb[3]);
      *(ushort4*)(w2hi + base + 4) = make_ushort4(hb[4], hb[5], hb[6], hb[7]);
      *(ushort4*)(w2lo + base)     = make_ushort4(lb[0], lb[1], lb[2], lb[3]);
      *(ushort4*)(w2lo + base + 4) = make_ushort4(lb[4], lb[5], lb[6], lb[7]);
    }
  }
}

// ---------------- GEMM1 via MFMA + fused s1 scores ---------------------------
// No LDS. All 16 x float4 loads issued up front (16 KB/wave in flight, register
// MLP), weight fragments register-prefetched one kt ahead. Compiler emits
// fine-grained vmcnt per consumer.
__global__ __launch_bounds__(256) void gemm1_mfma_kernel(
    const float* __restrict__ x, const unsigned short* __restrict__ whi,
    const unsigned short* __restrict__ wlo,
    const float* __restrict__ a_src, const float* __restrict__ a_dst,
    unsigned short* __restrict__ h1b,
    float* __restrict__ s_src, float* __restrict__ s_dst, int N) {
  const int w = threadIdx.x >> 6, lane = threadIdx.x & 63;
  const int m = lane & 15, g = lane >> 4;
  const int rbase = blockIdx.x * 64 + w * 16;
  int arow = rbase + m;
  if (arow >= N) arow = N - 1;
  const float* xrow = x + (size_t)arow * 256 + g * 8;

  // ---- issue ALL x loads up front: 16 x dwordx4 = 256 B/lane in flight ----
  float4 xa[16];
#pragma unroll
  for (int kt = 0; kt < 8; ++kt) {
    xa[2 * kt]     = *(const float4*)(xrow + kt * 32);
    xa[2 * kt + 1] = *(const float4*)(xrow + kt * 32 + 4);
  }

  // ---- weight fragment pointers + preload kt=0 batch ----
  const unsigned short* wp0 = whi + (size_t)lane * 8;
  const unsigned short* lp0 = wlo + (size_t)lane * 8;
  bf16x8 bh[4], bl[4];
#pragma unroll
  for (int ct = 0; ct < 4; ++ct) {
    bh[ct] = *(const bf16x8*)(wp0 + (size_t)ct * 512);
    bl[ct] = *(const bf16x8*)(lp0 + (size_t)ct * 512);
  }

  f32x4 acc[4] = {{0.f, 0.f, 0.f, 0.f}, {0.f, 0.f, 0.f, 0.f},
                  {0.f, 0.f, 0.f, 0.f}, {0.f, 0.f, 0.f, 0.f}};

#pragma unroll
  for (int kt = 0; kt < 8; ++kt) {
    // prefetch next kt's weight fragments (independent of this kt's compute)
    bf16x8 nh[4], nl[4];
    if (kt < 7) {
#pragma unroll
      for (int ct = 0; ct < 4; ++ct) {
        nh[ct] = *(const bf16x8*)(wp0 + (size_t)((kt + 1) * 4 + ct) * 512);
        nl[ct] = *(const bf16x8*)(lp0 + (size_t)((kt + 1) * 4 + ct) * 512);
      }
    }
    float4 a0 = xa[2 * kt];
    float4 a1 = xa[2 * kt + 1];
    float av[8] = {a0.x, a0.y, a0.z, a0.w, a1.x, a1.y, a1.z, a1.w};
    bf16x8 ahi, alo;
#pragma unroll
    for (int j = 0; j < 8; ++j) {
      unsigned int u = __float_as_uint(av[j]);
      unsigned short hi = (unsigned short)(u >> 16);      // truncate
      float rem = av[j] - bf2f(hi);
      ahi[j] = (short)hi;
      alo[j] = (short)(__float_as_uint(rem) >> 16);       // truncate residual
    }
#pragma unroll
    for (int ct = 0; ct < 4; ++ct) {
      acc[ct] = __builtin_amdgcn_mfma_f32_16x16x32_bf16(ahi, bh[ct], acc[ct], 0, 0, 0);
      acc[ct] = __builtin_amdgcn_mfma_f32_16x16x32_bf16(alo, bh[ct], acc[ct], 0, 0, 0);
      acc[ct] = __builtin_amdgcn_mfma_f32_16x16x32_bf16(ahi, bl[ct], acc[ct], 0, 0, 0);
    }
    if (kt < 7) {
#pragma unroll
      for (int ct = 0; ct < 4; ++ct) { bh[ct] = nh[ct]; bl[ct] = nl[ct]; }
    }
  }
  // ---- h1b stores ----
#pragma unroll
  for (int r = 0; r < 4; ++r) {
    int ro = rbase + g * 4 + r;
    if (ro < N) {
#pragma unroll
      for (int ct = 0; ct < 4; ++ct)
        h1b[(size_t)ro * 64 + ct * 16 + m] = f2bf(acc[ct][r]);
    }
  }
  // ---- fused s1: head h = ct*2 + (m>>3); its 8 dims live on the m&7 group ----
  float a1sv[4], a1dv[4];
#pragma unroll
  for (int ct = 0; ct < 4; ++ct) {
    a1sv[ct] = a_src[ct * 16 + m];
    a1dv[ct] = a_dst[ct * 16 + m];
  }
#pragma unroll
  for (int r = 0; r < 4; ++r) {
    float ps[4], pd[4];
#pragma unroll
    for (int ct = 0; ct < 4; ++ct) {
      ps[ct] = acc[ct][r] * a1sv[ct];
      pd[ct] = acc[ct][r] * a1dv[ct];
    }
#pragma unroll
    for (int off = 1; off < 8; off <<= 1) {
#pragma unroll
      for (int ct = 0; ct < 4; ++ct) {
        ps[ct] += __shfl_xor(ps[ct], off);
        pd[ct] += __shfl_xor(pd[ct], off);
      }
    }
    int ro = rbase + g * 4 + r;
    if ((m & 7) == 0 && ro < N) {
      int hb2 = m >> 3;       // 0 or 1
#pragma unroll
      for (int ct = 0; ct < 4; ++ct) {
        s_src[(size_t)ro * 8 + ct * 2 + hb2] = ps[ct];
        s_dst[(size_t)ro * 8 + ct * 2 + hb2] = pd[ct];
      }
    }
  }
}

// ---------------- bin edges into fixed-capacity bucket regions (staged) ------
__global__ __launch_bounds__(256) void bin_kernel(const int* __restrict__ src,
                                                  const int* __restrict__ dst,
                                                  int* __restrict__ bpos,
                                                  unsigned int* __restrict__ payload,
                                                  int E, int NB, int capP) {
  __shared__ int hist[MAXNB], soff[MAXNB], base[MAXNB], rnk[MAXNB];
  __shared__ unsigned int stage[4096];
  const int t = threadIdx.x;
  const int e0 = blockIdx.x * 4096;
  if (t < MAXNB) { hist[t] = 0; rnk[t] = 0; }
  __syncthreads();
  for (int j = t; j < 4096; j += 256) {
    int e = e0 + j;
    if (e < E) atomicAdd(&hist[dst[e] >> BK], 1);
  }
  __syncthreads();
  if (t == 0) {
    int acc = 0;
    for (int b = 0; b < NB; ++b) { soff[b] = acc; acc += hist[b]; }
  }
  __syncthreads();
  if (t < NB) {
    int c = hist[t];
    base[t] = c ? atomicAdd(&bpos[t], c) : 0;
  }
  __syncthreads();
  for (int j = t; j < 4096; j += 256) {
    int e = e0 + j;
    if (e < E) {
      int d = dst[e];
      int b = d >> BK;
      int s = src[e];
      int r = atomicAdd(&rnk[b], 1);
      stage[soff[b] + r] = (((unsigned)(d & (KNODES - 1))) << 17) | (unsigned)s;
    }
  }
  __syncthreads();
  int wave = t >> 6, lane = t & 63;
  for (int b = wave; b < NB; b += 4) {
    int len = hist[b], bs = soff[b], gb = base[b];
    int lim = (b + 1) * capP;
    for (int j = lane; j < len; j += 64)
      if (gb + j < lim) payload[gb + j] = stage[bs + j];   // overflow guard
  }
}

// ---------------- fill2: count + wave-shfl padded scan + scatter + pad -------
__global__ __launch_bounds__(1024) void fill2_kernel(const unsigned int* __restrict__ payload,
                                                     const int* __restrict__ bpos,
                                                     int* __restrict__ col,
                                                     int* __restrict__ rbeg,
                                                     int* __restrict__ rend,
                                                     int capP, int NN) {
  __shared__ int cnt[KNODES], pos[KNODES];
  __shared__ int wsum[16];
  const int b = blockIdx.x, t = threadIdx.x;
  cnt[t] = 0;
  __syncthreads();
  const int beg = b * capP;
  int len = bpos[b] - beg;
  if (len > capP) len = capP;
  for (int j = t; j < len; j += 1024) atomicAdd(&cnt[payload[beg + j] >> 17], 1);
  __syncthreads();
  const int myc = cnt[t];
  const int padc = (myc + 7) & ~7;
  const int lane = t & 63, wid = t >> 6;
  // wave-level inclusive scan of padc
  int v = padc;
#pragma unroll
  for (int off = 1; off < 64; off <<= 1) {
    int u = __shfl_up(v, off, 64);
    if (lane >= off) v += u;
  }
  if (lane == 63) wsum[wid] = v;
  __syncthreads();
  if (t < 16) {
    int sv = wsum[t];
#pragma unroll
    for (int off = 1; off < 16; off <<= 1) {
      int u = __shfl_up(sv, off, 64);
      if ((int)t >= off) sv += u;
    }
    wsum[t] = sv;
  }
  __syncthreads();
  const int incl = v + (wid ? wsum[wid - 1] : 0);               // inclusive scan
  const int mystart = b * (capP + 8 * KNODES) + incl - padc;    // exclusive
  const int n = (b << BK) + t;
  if (n < NN) { rbeg[n] = mystart; rend[n] = mystart + padc; }
  pos[t] = mystart;
  __syncthreads();
  for (int j = t; j < len; j += 1024) {
    unsigned int pay = payload[beg + j];
    int p = atomicAdd(&pos[pay >> 17], 1);
    col[p] = (int)(pay & 0x1FFFF);
  }
  __syncthreads();
  // sentinel-pad each row to padc (<=7 writes per node)
  for (int j = mystart + myc; j < mystart + padc; ++j) col[j] = NN;
}

// ---------------- layer-1 aggregation: lane-transposed scores, 16-deep -------
__global__ __launch_bounds__(256) void agg1_kernel(
    const int* __restrict__ rbeg, const int* __restrict__ rend,
    const int* __restrict__ col,
    const float* __restrict__ s_src, const float* __restrict__ s_dst,
    const unsigned short* __restrict__ h1b, const float* __restrict__ b1,
    const float* __restrict__ vas, const float* __restrict__ vad,
    unsigned short* __restrict__ helub, float* __restrict__ s2s,
    float* __restrict__ s2d, int N) {
  int wv = threadIdx.x >> 6;
  int l  = threadIdx.x & 63;
  int n  = blockIdx.x * 4 + wv;
  if (n >= N) return;
  const int q  = l >> 3;          // edge slot for score stream
  const int hh = l & 7;           // head for score stream
  const float sdq = s_dst[n * 8 + hh];
  const int beg = __builtin_amdgcn_readfirstlane(rbeg[n]);
  const int end = __builtin_amdgcn_readfirstlane(rend[n]);
  float z = 0.f, acc = 0.f, acc2 = 0.f;
  int e = beg;
  if (((end - beg) >> 3) & 1) {   // odd 8-block first (wave-uniform branch)
    int4 ia = *(const int4*)(col + e);
    int4 ib = *(const int4*)(col + e + 4);
    int myidx = col[e + q];
    float pv = s_src[(unsigned)myidx * 8u + (unsigned)hh];
    float tt = pv + sdq;
    tt = fmaxf(tt, 0.2f * tt);
    float w = __expf(tt);
    z += w;
    int idxs[8] = {ia.x, ia.y, ia.z, ia.w, ib.x, ib.y, ib.z, ib.w};
#pragma unroll
    for (int j = 0; j < 8; ++j) {
      float wj = __shfl(w, j * 8 + q, 64);
      unsigned short g = h1b[(unsigned)idxs[j] * 64u + (unsigned)l];
      acc = fmaf(wj, bf2f(g), acc);
    }
    e += 8;
  }
  for (; e < end; e += 16) {
    int4 ia = *(const int4*)(col + e);
    int4 ib = *(const int4*)(col + e + 4);
    int4 ic = *(const int4*)(col + e + 8);
    int4 id = *(const int4*)(col + e + 12);
    int my0 = col[e + q];
    int my1 = col[e + 8 + q];
    float pv0 = s_src[(unsigned)my0 * 8u + (unsigned)hh];
    float pv1 = s_src[(unsigned)my1 * 8u + (unsigned)hh];
    int idxs[16] = {ia.x, ia.y, ia.z, ia.w, ib.x, ib.y, ib.z, ib.w,
                    ic.x, ic.y, ic.z, ic.w, id.x, id.y, id.z, id.w};
    unsigned short gg[16];
#pragma unroll
    for (int j = 0; j < 16; ++j) gg[j] = h1b[(unsigned)idxs[j] * 64u + (unsigned)l];
    float t0 = pv0 + sdq; t0 = fmaxf(t0, 0.2f * t0); float w0 = __expf(t0);
    float t1 = pv1 + sdq; t1 = fmaxf(t1, 0.2f * t1); float w1 = __expf(t1);
    z += w0 + w1;
#pragma unroll
    for (int j = 0; j < 8; ++j) {
      float wj = __shfl(w0, j * 8 + q, 64);
      acc = fmaf(wj, bf2f(gg[j]), acc);
    }
#pragma unroll
    for (int j = 0; j < 8; ++j) {
      float wj = __shfl(w1, j * 8 + q, 64);
      acc2 = fmaf(wj, bf2f(gg[8 + j]), acc2);
    }
  }
  acc += acc2;
  z += __shfl_xor(z, 8); z += __shfl_xor(z, 16); z += __shfl_xor(z, 32);
  float zf = __shfl(z, 9 * q, 64);
  float v = acc / (zf + 1e-16f) + b1[l];
  v = v > 0.f ? v : (__expf(v) - 1.f);       // elu
  helub[(size_t)n * 64 + l] = f2bf(v);
  float ps = v * vas[l];
  float pd = v * vad[l];
  for (int off = 32; off > 0; off >>= 1) {
    ps += __shfl_xor(ps, off);
    pd += __shfl_xor(pd, off);
  }
  if (l == 0) { s2s[n] = ps; s2d[n] = pd; }
}

// ---------------- GEMM2 via MFMA: h2b[N,40](bf16) = helub[N,64] @ W2 ---------
__global__ __launch_bounds__(256) void gemm2_mfma_kernel(
    const unsigned short* __restrict__ heb, const unsigned short* __restrict__ w2hi,
    const unsigned short* __restrict__ w2lo, unsigned short* __restrict__ h2b, int N) {
  const int w = threadIdx.x >> 6, lane = threadIdx.x & 63;
  const int m = lane & 15, g = lane >> 4;
  const int rbase = blockIdx.x * 64 + w * 16;
  int arow = rbase + m;
  if (arow >= N) arow = N - 1;
  const unsigned short* hrow = heb + (size_t)arow * 64 + g * 8;
  f32x4 acc[3] = {{0.f, 0.f, 0.f, 0.f}, {0.f, 0.f, 0.f, 0.f}, {0.f, 0.f, 0.f, 0.f}};
#pragma unroll
  for (int kt = 0; kt < 2; ++kt) {
    bf16x8 a = *(const bf16x8*)(hrow + kt * 32);
#pragma unroll
    for (int ct = 0; ct < 3; ++ct) {
      int b = kt * 3 + ct;
      bf16x8 bh = *(const bf16x8*)(w2hi + ((size_t)b * 64 + lane) * 8);
      bf16x8 bl = *(const bf16x8*)(w2lo + ((size_t)b * 64 + lane) * 8);
      acc[ct] = __builtin_amdgcn_mfma_f32_16x16x32_bf16(a, bh, acc[ct], 0, 0, 0);
      acc[ct] = __builtin_amdgcn_mfma_f32_16x16x32_bf16(a, bl, acc[ct], 0, 0, 0);
    }
  }
#pragma unroll
  for (int r = 0; r < 4; ++r) {
    int ro = rbase + g * 4 + r;
    if (ro < N) {
#pragma unroll
      for (int ct = 0; ct < 3; ++ct) {
        int c = ct * 16 + m;
        if (c < 40) h2b[(size_t)ro * 40 + c] = f2bf(acc[ct][r]);
      }
    }
  }
}

// ---------------- layer-2 aggregation + log_softmax (16-deep) ----------------
__global__ __launch_bounds__(256) void agg2_kernel(
    const int* __restrict__ rbeg, const int* __restrict__ rend,
    const int* __restrict__ col,
    const float* __restrict__ s2s, const float* __restrict__ s2d,
    const unsigned short* __restrict__ h2b, const float* __restrict__ b2,
    float* __restrict__ out, int N) {
  int wv = threadIdx.x >> 6;
  int l  = threadIdx.x & 63;
  int n  = blockIdx.x * 4 + wv;
  if (n >= N) return;
  const int q = l >> 3;
  const bool act = (l < 40);
  const unsigned lc = act ? (unsigned)l : 0u;
  const float sdv = s2d[n];
  const int beg = __builtin_amdgcn_readfirstlane(rbeg[n]);
  const int end = __builtin_amdgcn_readfirstlane(rend[n]);
  float z = 0.f, acc = 0.f, acc2 = 0.f;
  int e = beg;
  if (((end - beg) >> 3) & 1) {
    int4 ia = *(const int4*)(col + e);
    int4 ib = *(const int4*)(col + e + 4);
    int myidx = col[e + q];
    float pv = s2s[myidx];
    float tt = pv + sdv;
    tt = fmaxf(tt, 0.2f * tt);
    float w = __expf(tt);
    z += w;
    int idxs[8] = {ia.x, ia.y, ia.z, ia.w, ib.x, ib.y, ib.z, ib.w};
#pragma unroll
    for (int j = 0; j < 8; ++j) {
      float wj = __shfl(w, j * 8, 64);
      unsigned short g = h2b[(unsigned)idxs[j] * 40u + lc];
      acc = fmaf(wj, bf2f(g), acc);
    }
    e += 8;
  }
  for (; e < end; e += 16) {
    int4 ia = *(const int4*)(col + e);
    int4 ib = *(const int4*)(col + e + 4);
    int4 ic = *(const int4*)(col + e + 8);
    int4 id = *(const int4*)(col + e + 12);
    int my0 = col[e + q];
    int my1 = col[e + 8 + q];
    float pv0 = s2s[my0];
    float pv1 = s2s[my1];
    int idxs[16] = {ia.x, ia.y, ia.z, ia.w, ib.x, ib.y, ib.z, ib.w,
                    ic.x, ic.y, ic.z, ic.w, id.x, id.y, id.z, id.w};
    unsigned short gg[16];
#pragma unroll
    for (int j = 0; j < 16; ++j) gg[j] = h2b[(unsigned)idxs[j] * 40u + lc];
    float t0 = pv0 + sdv; t0 = fmaxf(t0, 0.2f * t0); float w0 = __expf(t0);
    float t1 = pv1 + sdv; t1 = fmaxf(t1, 0.2f * t1); float w1 = __expf(t1);
    z += w0 + w1;
#pragma unroll
    for (int j = 0; j < 8; ++j) {
      float wj = __shfl(w0, j * 8, 64);
      acc = fmaf(wj, bf2f(gg[j]), acc);
    }
#pragma unroll
    for (int j = 0; j < 8; ++j) {
      float wj = __shfl(w1, j * 8, 64);
      acc2 = fmaf(wj, bf2f(gg[8 + j]), acc2);
    }
  }
  acc += acc2;
  z += __shfl_xor(z, 8); z += __shfl_xor(z, 16); z += __shfl_xor(z, 32);  // all lanes: Z
  float v = act ? (acc / (z + 1e-16f) + b2[l]) : -1e30f;
  float m = v;
  for (int off = 32; off > 0; off >>= 1) m = fmaxf(m, __shfl_xor(m, off));
  float ex = act ? __expf(v - m) : 0.f;
  float s = ex;
  for (int off = 32; off > 0; off >>= 1) s += __shfl_xor(s, off);
  if (act) out[(size_t)n * 40 + l] = v - m - logf(s);
}

// ---------------- launch -----------------------------------------------------
extern "C" void kernel_launch(void* const* d_in, const int* in_sizes, int n_in,
                              void* d_out, int out_size, void* d_ws, size_t ws_size,
                              hipStream_t stream) {
  const float* x   = (const float*)d_in[0];
  const int*   ei  = (const int*)d_in[1];
  const float* W1  = (const float*)d_in[2];
  const float* a1s = (const float*)d_in[3];
  const float* a1d = (const float*)d_in[4];
  const float* b1  = (const float*)d_in[5];
  const float* W2  = (const float*)d_in[6];
  const float* a2s = (const float*)d_in[7];
  const float* a2d = (const float*)d_in[8];
  const float* b2  = (const float*)d_in[9];
  float* out = (float*)d_out;
  (void)n_in; (void)out_size; (void)ws_size;

  const int NN = in_sizes[0] / 256;
  const int E  = in_sizes[1] / 2;
  const int NB = (NN + KNODES - 1) >> BK;
  const int* esrc = ei;
  const int* edst = ei + E;

  // fixed per-bucket payload capacity: mean + 31% + 512 (>>30 sigma for iid edges)
  int capP = (E + NB - 1) / NB;
  capP += capP / 4 + capP / 16 + 512;
  capP = (capP + 15) & ~15;

  char* p = (char*)d_ws;
  auto alloc = [&](size_t bytes) -> char* {
    char* q = p;
    p += (bytes + 255) & ~(size_t)255;
    return q;
  };
  unsigned short* h1b   = (unsigned short*)alloc((size_t)(NN + 1) * 64 * 2);
  unsigned short* helub = (unsigned short*)alloc((size_t)NN * 64 * 2);
  unsigned short* h2b   = (unsigned short*)alloc((size_t)(NN + 1) * 40 * 2);
  float* s1s  = (float*)alloc((size_t)(NN + 1) * 8 * 4);
  float* s1d  = (float*)alloc((size_t)NN * 8 * 4);
  float* s2s  = (float*)alloc((size_t)(NN + 1) * 4);
  float* s2d  = (float*)alloc((size_t)NN * 4);
  int*   rbeg = (int*)alloc((size_t)NN * 4);
  int*   rend = (int*)alloc((size_t)NN * 4);
  int*   bpos = (int*)alloc(MAXNB * 4);
  unsigned int* payload = (unsigned int*)alloc((size_t)NB * capP * 4);
  int*   col  = (int*)alloc((size_t)NB * (capP + 8 * KNODES) * 4);
  float* vas  = (float*)alloc(64 * 4);
  float* vad  = (float*)alloc(64 * 4);
  unsigned short* w1hi = (unsigned short*)alloc(32 * 64 * 8 * 2);
  unsigned short* w1lo = (unsigned short*)alloc(32 * 64 * 8 * 2);
  unsigned short* w2hi = (unsigned short*)alloc(6 * 64 * 8 * 2);
  unsigned short* w2lo = (unsigned short*)alloc(6 * 64 * 8 * 2);

  // 1) prep (bpos init, W1/W2 frags, va, sentinels)
  prep_kernel<<<40, 256, 0, stream>>>(W1, W2, a2s, a2d, w1hi, w1lo, w2hi, w2lo,
                                      vas, vad, h1b, h2b, s1s, s2s, bpos, capP, NN);
  // 2-3) CSR build
  bin_kernel<<<(E + 4095) / 4096, 256, 0, stream>>>(esrc, edst, bpos, payload, E, NB, capP);
  fill2_kernel<<<NB, 1024, 0, stream>>>(payload, bpos, col, rbeg, rend, capP, NN);
  // 4-7) dense math + aggregations (s1 fused into gemm1)
  gemm1_mfma_kernel<<<(NN + 63) / 64, 256, 0, stream>>>(x, w1hi, w1lo, a1s, a1d,
                                                        h1b, s1s, s1d, NN);
  agg1_kernel<<<(NN + 3) / 4, 256, 0, stream>>>(rbeg, rend, col, s1s, s1d, h1b, b1,
                                                vas, vad, helub, s2s, s2d, NN);
  gemm2_mfma_kernel<<<(NN + 63) / 64, 256, 0, stream>>>(helub, w2hi, w2lo, h2b, NN);
  agg2_kernel<<<(NN + 3) / 4, 256, 0, stream>>>(rbeg, rend, col, s2s, s2d, h2b, b2, out, NN);
}

// Round 5
// 353.442 us; speedup vs baseline: 1.0094x; 1.0094x over previous
//
#include <hip/hip_runtime.h>
#include <math.h>

#define BK 10
#define KNODES 1024   // nodes per bucket
#define MAXNB 128     // max buckets (N <= 131072, src fits 17 bits)

typedef __attribute__((ext_vector_type(8))) short bf16x8;
typedef __attribute__((ext_vector_type(4))) float f32x4;

// ---- bf16 helpers ----------------------------------------------------------
__device__ __forceinline__ float bf2f(unsigned short u) {
  return __uint_as_float(((unsigned int)u) << 16);
}
__device__ __forceinline__ unsigned short f2bf(float f) {
  unsigned int i = __float_as_uint(f);
  unsigned int r = i + 0x7FFFu + ((i >> 16) & 1u);   // round-to-nearest-even
  return (unsigned short)(r >> 16);
}

// ---------------- prep: bpos init + W1/W2 frags + va + sentinels (1 launch) --
__global__ __launch_bounds__(256) void prep_kernel(
    const float* __restrict__ W1, const float* __restrict__ W2,
    const float* __restrict__ a2s, const float* __restrict__ a2d,
    unsigned short* __restrict__ whi, unsigned short* __restrict__ wlo,
    unsigned short* __restrict__ w2hi, unsigned short* __restrict__ w2lo,
    float* __restrict__ vas, float* __restrict__ vad,
    unsigned short* __restrict__ h1b, unsigned short* __restrict__ h2b,
    float* __restrict__ s1s, float* __restrict__ s2s,
    int* __restrict__ bpos, int capP, int NN) {
  const int blk = blockIdx.x, t = threadIdx.x;
  if (blk == 0 && t < MAXNB) bpos[t] = t * capP;
  if (blk < 32) {
    if (t < 64) {
      // W1 -> MFMA B-frag layout, hi/lo bf16 split. tile b=kt*4+ct
      int b = blk, lane = t;
      int kt = b >> 2, ct = b & 3;
      int n = lane & 15, g = lane >> 4;
      unsigned short hb[8], lb[8];
#pragma unroll
      for (int j = 0; j < 8; ++j) {
        int k = kt * 32 + g * 8 + j;
        float wv = W1[k * 64 + ct * 16 + n];
        unsigned short hi = f2bf(wv);
        float rem = wv - bf2f(hi);
        hb[j] = hi;
        lb[j] = f2bf(rem);
      }
      size_t base = ((size_t)b * 64 + lane) * 8;
      *(ushort4*)(whi + base)     = make_ushort4(hb[0], hb[1], hb[2], hb[3]);
      *(ushort4*)(whi + base + 4) = make_ushort4(hb[4], hb[5], hb[6], hb[7]);
      *(ushort4*)(wlo + base)     = make_ushort4(lb[0], lb[1], lb[2], lb[3]);
      *(ushort4*)(wlo + base + 4) = make_ushort4(lb[4], lb[5], lb[6], lb[7]);
    }
  } else if (blk == 32) {
    if (t < 64) {
      float s = 0.f, d = 0.f;
      for (int c = 0; c < 40; ++c) {
        float w = W2[t * 40 + c];
        s += w * a2s[c];
        d += w * a2d[c];
      }
      vas[t] = s;
      vad[t] = d;
    }
  } else if (blk == 33) {
    if (t < 64) {
      h1b[(size_t)NN * 64 + t] = 0;
      if (t < 40) h2b[(size_t)NN * 40 + t] = 0;
      if (t < 8)  s1s[(size_t)NN * 8 + t] = -1e30f;
      if (t == 0) s2s[NN] = -1e30f;
    }
  } else if (blk >= 34 && blk < 40) {
    if (t < 64) {
      // W2 -> MFMA B-frag layout, hi/lo bf16 split. tile b = kt*3+ct (kt<2, ct<3)
      int b = blk - 34;
      int kt = b / 3, ct = b % 3;
      int n = t & 15, g = t >> 4;
      unsigned short hb[8], lb[8];
#pragma unroll
      for (int j = 0; j < 8; ++j) {
        int k = kt * 32 + g * 8 + j;          // < 64
        int c = ct * 16 + n;
        float wv = (c < 40) ? W2[k * 40 + c] : 0.f;
        unsigned short hi = f2bf(wv);
        float rem = wv - bf2f(hi);
        hb[j] = hi;
        lb[j] = f2bf(rem);
      }
      size_t base = ((size_t)b * 64 + t) * 8;
      *(ushort4*)(w2hi + base)     = make_ushort4(hb[0], hb[1], hb[2], hb[3]);
      *(ushort4*)(w2hi + base + 4) = make_ushort4(hb[4], hb[5], hb[6], hb[7]);
      *(ushort4*)(w2lo + base)     = make_ushort4(lb[0], lb[1], lb[2], lb[3]);
      *(ushort4*)(w2lo + base + 4) = make_ushort4(lb[4], lb[5], lb[6], lb[7]);
    }
  }
}

// ---------------- GEMM1 via MFMA + fused s1 scores ---------------------------
// No LDS. All 16 x float4 loads issued up front (16 KB/wave in flight, register
// MLP), weight fragments register-prefetched one kt ahead.
// __launch_bounds__(256,2) lifts the VGPR cap to 256 so the allocator can keep
// them live; sched_barrier(0) pins the issue order. waitcnt pass then emits the
// counted vmcnt ladder per consumer.
__global__ __launch_bounds__(256, 2) void gemm1_mfma_kernel(
    const float* __restrict__ x, const unsigned short* __restrict__ whi,
    const unsigned short* __restrict__ wlo,
    const float* __restrict__ a_src, const float* __restrict__ a_dst,
    unsigned short* __restrict__ h1b,
    float* __restrict__ s_src, float* __restrict__ s_dst, int N) {
  const int w = threadIdx.x >> 6, lane = threadIdx.x & 63;
  const int m = lane & 15, g = lane >> 4;
  const int rbase = blockIdx.x * 64 + w * 16;
  int arow = rbase + m;
  if (arow >= N) arow = N - 1;
  const float* xrow = x + (size_t)arow * 256 + g * 8;

  // ---- issue ALL x loads up front: 16 x dwordx4 = 256 B/lane in flight ----
  float4 xa[16];
#pragma unroll
  for (int kt = 0; kt < 8; ++kt) {
    xa[2 * kt]     = *(const float4*)(xrow + kt * 32);
    xa[2 * kt + 1] = *(const float4*)(xrow + kt * 32 + 4);
  }

  // ---- weight fragment pointers + preload kt=0 batch ----
  const unsigned short* wp0 = whi + (size_t)lane * 8;
  const unsigned short* lp0 = wlo + (size_t)lane * 8;
  bf16x8 bh[4], bl[4];
#pragma unroll
  for (int ct = 0; ct < 4; ++ct) {
    bh[ct] = *(const bf16x8*)(wp0 + (size_t)ct * 512);
    bl[ct] = *(const bf16x8*)(lp0 + (size_t)ct * 512);
  }
  // pin: all of the above loads are ISSUED before anything below is scheduled
  __builtin_amdgcn_sched_barrier(0);

  f32x4 acc[4] = {{0.f, 0.f, 0.f, 0.f}, {0.f, 0.f, 0.f, 0.f},
                  {0.f, 0.f, 0.f, 0.f}, {0.f, 0.f, 0.f, 0.f}};

#pragma unroll
  for (int kt = 0; kt < 8; ++kt) {
    // prefetch next kt's weight fragments (independent of this kt's compute)
    bf16x8 nh[4], nl[4];
    if (kt < 7) {
#pragma unroll
      for (int ct = 0; ct < 4; ++ct) {
        nh[ct] = *(const bf16x8*)(wp0 + (size_t)((kt + 1) * 4 + ct) * 512);
        nl[ct] = *(const bf16x8*)(lp0 + (size_t)((kt + 1) * 4 + ct) * 512);
      }
    }
    float4 a0 = xa[2 * kt];
    float4 a1 = xa[2 * kt + 1];
    float av[8] = {a0.x, a0.y, a0.z, a0.w, a1.x, a1.y, a1.z, a1.w};
    bf16x8 ahi, alo;
#pragma unroll
    for (int j = 0; j < 8; ++j) {
      unsigned int u = __float_as_uint(av[j]);
      unsigned short hi = (unsigned short)(u >> 16);      // truncate
      float rem = av[j] - bf2f(hi);
      ahi[j] = (short)hi;
      alo[j] = (short)(__float_as_uint(rem) >> 16);       // truncate residual
    }
#pragma unroll
    for (int ct = 0; ct < 4; ++ct) {
      acc[ct] = __builtin_amdgcn_mfma_f32_16x16x32_bf16(ahi, bh[ct], acc[ct], 0, 0, 0);
      acc[ct] = __builtin_amdgcn_mfma_f32_16x16x32_bf16(alo, bh[ct], acc[ct], 0, 0, 0);
      acc[ct] = __builtin_amdgcn_mfma_f32_16x16x32_bf16(ahi, bl[ct], acc[ct], 0, 0, 0);
    }
    if (kt < 7) {
#pragma unroll
      for (int ct = 0; ct < 4; ++ct) { bh[ct] = nh[ct]; bl[ct] = nl[ct]; }
    }
  }
  // ---- h1b stores ----
#pragma unroll
  for (int r = 0; r < 4; ++r) {
    int ro = rbase + g * 4 + r;
    if (ro < N) {
#pragma unroll
      for (int ct = 0; ct < 4; ++ct)
        h1b[(size_t)ro * 64 + ct * 16 + m] = f2bf(acc[ct][r]);
    }
  }
  // ---- fused s1: head h = ct*2 + (m>>3); its 8 dims live on the m&7 group ----
  float a1sv[4], a1dv[4];
#pragma unroll
  for (int ct = 0; ct < 4; ++ct) {
    a1sv[ct] = a_src[ct * 16 + m];
    a1dv[ct] = a_dst[ct * 16 + m];
  }
#pragma unroll
  for (int r = 0; r < 4; ++r) {
    float ps[4], pd[4];
#pragma unroll
    for (int ct = 0; ct < 4; ++ct) {
      ps[ct] = acc[ct][r] * a1sv[ct];
      pd[ct] = acc[ct][r] * a1dv[ct];
    }
#pragma unroll
    for (int off = 1; off < 8; off <<= 1) {
#pragma unroll
      for (int ct = 0; ct < 4; ++ct) {
        ps[ct] += __shfl_xor(ps[ct], off);
        pd[ct] += __shfl_xor(pd[ct], off);
      }
    }
    int ro = rbase + g * 4 + r;
    if ((m & 7) == 0 && ro < N) {
      int hb2 = m >> 3;       // 0 or 1
#pragma unroll
      for (int ct = 0; ct < 4; ++ct) {
        s_src[(size_t)ro * 8 + ct * 2 + hb2] = ps[ct];
        s_dst[(size_t)ro * 8 + ct * 2 + hb2] = pd[ct];
      }
    }
  }
}

// ---------------- bin edges into fixed-capacity bucket regions (staged) ------
__global__ __launch_bounds__(256) void bin_kernel(const int* __restrict__ src,
                                                  const int* __restrict__ dst,
                                                  int* __restrict__ bpos,
                                                  unsigned int* __restrict__ payload,
                                                  int E, int NB, int capP) {
  __shared__ int hist[MAXNB], soff[MAXNB], base[MAXNB], rnk[MAXNB];
  __shared__ unsigned int stage[4096];
  const int t = threadIdx.x;
  const int e0 = blockIdx.x * 4096;
  if (t < MAXNB) { hist[t] = 0; rnk[t] = 0; }
  __syncthreads();
  for (int j = t; j < 4096; j += 256) {
    int e = e0 + j;
    if (e < E) atomicAdd(&hist[dst[e] >> BK], 1);
  }
  __syncthreads();
  if (t == 0) {
    int acc = 0;
    for (int b = 0; b < NB; ++b) { soff[b] = acc; acc += hist[b]; }
  }
  __syncthreads();
  if (t < NB) {
    int c = hist[t];
    base[t] = c ? atomicAdd(&bpos[t], c) : 0;
  }
  __syncthreads();
  for (int j = t; j < 4096; j += 256) {
    int e = e0 + j;
    if (e < E) {
      int d = dst[e];
      int b = d >> BK;
      int s = src[e];
      int r = atomicAdd(&rnk[b], 1);
      stage[soff[b] + r] = (((unsigned)(d & (KNODES - 1))) << 17) | (unsigned)s;
    }
  }
  __syncthreads();
  int wave = t >> 6, lane = t & 63;
  for (int b = wave; b < NB; b += 4) {
    int len = hist[b], bs = soff[b], gb = base[b];
    int lim = (b + 1) * capP;
    for (int j = lane; j < len; j += 64)
      if (gb + j < lim) payload[gb + j] = stage[bs + j];   // overflow guard
  }
}

// ---------------- fill2: count + wave-shfl padded scan + scatter + pad -------
__global__ __launch_bounds__(1024) void fill2_kernel(const unsigned int* __restrict__ payload,
                                                     const int* __restrict__ bpos,
                                                     int* __restrict__ col,
                                                     int* __restrict__ rbeg,
                                                     int* __restrict__ rend,
                                                     int capP, int NN) {
  __shared__ int cnt[KNODES], pos[KNODES];
  __shared__ int wsum[16];
  const int b = blockIdx.x, t = threadIdx.x;
  cnt[t] = 0;
  __syncthreads();
  const int beg = b * capP;
  int len = bpos[b] - beg;
  if (len > capP) len = capP;
  for (int j = t; j < len; j += 1024) atomicAdd(&cnt[payload[beg + j] >> 17], 1);
  __syncthreads();
  const int myc = cnt[t];
  const int padc = (myc + 7) & ~7;
  const int lane = t & 63, wid = t >> 6;
  // wave-level inclusive scan of padc
  int v = padc;
#pragma unroll
  for (int off = 1; off < 64; off <<= 1) {
    int u = __shfl_up(v, off, 64);
    if (lane >= off) v += u;
  }
  if (lane == 63) wsum[wid] = v;
  __syncthreads();
  if (t < 16) {
    int sv = wsum[t];
#pragma unroll
    for (int off = 1; off < 16; off <<= 1) {
      int u = __shfl_up(sv, off, 64);
      if ((int)t >= off) sv += u;
    }
    wsum[t] = sv;
  }
  __syncthreads();
  const int incl = v + (wid ? wsum[wid - 1] : 0);               // inclusive scan
  const int mystart = b * (capP + 8 * KNODES) + incl - padc;    // exclusive
  const int n = (b << BK) + t;
  if (n < NN) { rbeg[n] = mystart; rend[n] = mystart + padc; }
  pos[t] = mystart;
  __syncthreads();
  for (int j = t; j < len; j += 1024) {
    unsigned int pay = payload[beg + j];
    int p = atomicAdd(&pos[pay >> 17], 1);
    col[p] = (int)(pay & 0x1FFFF);
  }
  __syncthreads();
  // sentinel-pad each row to padc (<=7 writes per node)
  for (int j = mystart + myc; j < mystart + padc; ++j) col[j] = NN;
}

// ---------------- layer-1 aggregation: lane-transposed scores, 16-deep -------
__global__ __launch_bounds__(256) void agg1_kernel(
    const int* __restrict__ rbeg, const int* __restrict__ rend,
    const int* __restrict__ col,
    const float* __restrict__ s_src, const float* __restrict__ s_dst,
    const unsigned short* __restrict__ h1b, const float* __restrict__ b1,
    const float* __restrict__ vas, const float* __restrict__ vad,
    unsigned short* __restrict__ helub, float* __restrict__ s2s,
    float* __restrict__ s2d, int N) {
  int wv = threadIdx.x >> 6;
  int l  = threadIdx.x & 63;
  int n  = blockIdx.x * 4 + wv;
  if (n >= N) return;
  const int q  = l >> 3;          // edge slot for score stream
  const int hh = l & 7;           // head for score stream
  const float sdq = s_dst[n * 8 + hh];
  const int beg = __builtin_amdgcn_readfirstlane(rbeg[n]);
  const int end = __builtin_amdgcn_readfirstlane(rend[n]);
  float z = 0.f, acc = 0.f, acc2 = 0.f;
  int e = beg;
  if (((end - beg) >> 3) & 1) {   // odd 8-block first (wave-uniform branch)
    int4 ia = *(const int4*)(col + e);
    int4 ib = *(const int4*)(col + e + 4);
    int myidx = col[e + q];
    float pv = s_src[(unsigned)myidx * 8u + (unsigned)hh];
    float tt = pv + sdq;
    tt = fmaxf(tt, 0.2f * tt);
    float w = __expf(tt);
    z += w;
    int idxs[8] = {ia.x, ia.y, ia.z, ia.w, ib.x, ib.y, ib.z, ib.w};
#pragma unroll
    for (int j = 0; j < 8; ++j) {
      float wj = __shfl(w, j * 8 + q, 64);
      unsigned short g = h1b[(unsigned)idxs[j] * 64u + (unsigned)l];
      acc = fmaf(wj, bf2f(g), acc);
    }
    e += 8;
  }
  for (; e < end; e += 16) {
    int4 ia = *(const int4*)(col + e);
    int4 ib = *(const int4*)(col + e + 4);
    int4 ic = *(const int4*)(col + e + 8);
    int4 id = *(const int4*)(col + e + 12);
    int my0 = col[e + q];
    int my1 = col[e + 8 + q];
    float pv0 = s_src[(unsigned)my0 * 8u + (unsigned)hh];
    float pv1 = s_src[(unsigned)my1 * 8u + (unsigned)hh];
    int idxs[16] = {ia.x, ia.y, ia.z, ia.w, ib.x, ib.y, ib.z, ib.w,
                    ic.x, ic.y, ic.z, ic.w, id.x, id.y, id.z, id.w};
    unsigned short gg[16];
#pragma unroll
    for (int j = 0; j < 16; ++j) gg[j] = h1b[(unsigned)idxs[j] * 64u + (unsigned)l];
    float t0 = pv0 + sdq; t0 = fmaxf(t0, 0.2f * t0); float w0 = __expf(t0);
    float t1 = pv1 + sdq; t1 = fmaxf(t1, 0.2f * t1); float w1 = __expf(t1);
    z += w0 + w1;
#pragma unroll
    for (int j = 0; j < 8; ++j) {
      float wj = __shfl(w0, j * 8 + q, 64);
      acc = fmaf(wj, bf2f(gg[j]), acc);
    }
#pragma unroll
    for (int j = 0; j < 8; ++j) {
      float wj = __shfl(w1, j * 8 + q, 64);
      acc2 = fmaf(wj, bf2f(gg[8 + j]), acc2);
    }
  }
  acc += acc2;
  z += __shfl_xor(z, 8); z += __shfl_xor(z, 16); z += __shfl_xor(z, 32);
  float zf = __shfl(z, 9 * q, 64);
  float v = acc / (zf + 1e-16f) + b1[l];
  v = v > 0.f ? v : (__expf(v) - 1.f);       // elu
  helub[(size_t)n * 64 + l] = f2bf(v);
  float ps = v * vas[l];
  float pd = v * vad[l];
  for (int off = 32; off > 0; off >>= 1) {
    ps += __shfl_xor(ps, off);
    pd += __shfl_xor(pd, off);
  }
  if (l == 0) { s2s[n] = ps; s2d[n] = pd; }
}

// ---------------- GEMM2 via MFMA: h2b[N,40](bf16) = helub[N,64] @ W2 ---------
__global__ __launch_bounds__(256) void gemm2_mfma_kernel(
    const unsigned short* __restrict__ heb, const unsigned short* __restrict__ w2hi,
    const unsigned short* __restrict__ w2lo, unsigned short* __restrict__ h2b, int N) {
  const int w = threadIdx.x >> 6, lane = threadIdx.x & 63;
  const int m = lane & 15, g = lane >> 4;
  const int rbase = blockIdx.x * 64 + w * 16;
  int arow = rbase + m;
  if (arow >= N) arow = N - 1;
  const unsigned short* hrow = heb + (size_t)arow * 64 + g * 8;
  f32x4 acc[3] = {{0.f, 0.f, 0.f, 0.f}, {0.f, 0.f, 0.f, 0.f}, {0.f, 0.f, 0.f, 0.f}};
#pragma unroll
  for (int kt = 0; kt < 2; ++kt) {
    bf16x8 a = *(const bf16x8*)(hrow + kt * 32);
#pragma unroll
    for (int ct = 0; ct < 3; ++ct) {
      int b = kt * 3 + ct;
      bf16x8 bh = *(const bf16x8*)(w2hi + ((size_t)b * 64 + lane) * 8);
      bf16x8 bl = *(const bf16x8*)(w2lo + ((size_t)b * 64 + lane) * 8);
      acc[ct] = __builtin_amdgcn_mfma_f32_16x16x32_bf16(a, bh, acc[ct], 0, 0, 0);
      acc[ct] = __builtin_amdgcn_mfma_f32_16x16x32_bf16(a, bl, acc[ct], 0, 0, 0);
    }
  }
#pragma unroll
  for (int r = 0; r < 4; ++r) {
    int ro = rbase + g * 4 + r;
    if (ro < N) {
#pragma unroll
      for (int ct = 0; ct < 3; ++ct) {
        int c = ct * 16 + m;
        if (c < 40) h2b[(size_t)ro * 40 + c] = f2bf(acc[ct][r]);
      }
    }
  }
}

// ---------------- layer-2 aggregation + log_softmax (16-deep) ----------------
__global__ __launch_bounds__(256) void agg2_kernel(
    const int* __restrict__ rbeg, const int* __restrict__ rend,
    const int* __restrict__ col,
    const float* __restrict__ s2s, const float* __restrict__ s2d,
    const unsigned short* __restrict__ h2b, const float* __restrict__ b2,
    float* __restrict__ out, int N) {
  int wv = threadIdx.x >> 6;
  int l  = threadIdx.x & 63;
  int n  = blockIdx.x * 4 + wv;
  if (n >= N) return;
  const int q = l >> 3;
  const bool act = (l < 40);
  const unsigned lc = act ? (unsigned)l : 0u;
  const float sdv = s2d[n];
  const int beg = __builtin_amdgcn_readfirstlane(rbeg[n]);
  const int end = __builtin_amdgcn_readfirstlane(rend[n]);
  float z = 0.f, acc = 0.f, acc2 = 0.f;
  int e = beg;
  if (((end - beg) >> 3) & 1) {
    int4 ia = *(const int4*)(col + e);
    int4 ib = *(const int4*)(col + e + 4);
    int myidx = col[e + q];
    float pv = s2s[myidx];
    float tt = pv + sdv;
    tt = fmaxf(tt, 0.2f * tt);
    float w = __expf(tt);
    z += w;
    int idxs[8] = {ia.x, ia.y, ia.z, ia.w, ib.x, ib.y, ib.z, ib.w};
#pragma unroll
    for (int j = 0; j < 8; ++j) {
      float wj = __shfl(w, j * 8, 64);
      unsigned short g = h2b[(unsigned)idxs[j] * 40u + lc];
      acc = fmaf(wj, bf2f(g), acc);
    }
    e += 8;
  }
  for (; e < end; e += 16) {
    int4 ia = *(const int4*)(col + e);
    int4 ib = *(const int4*)(col + e + 4);
    int4 ic = *(const int4*)(col + e + 8);
    int4 id = *(const int4*)(col + e + 12);
    int my0 = col[e + q];
    int my1 = col[e + 8 + q];
    float pv0 = s2s[my0];
    float pv1 = s2s[my1];
    int idxs[16] = {ia.x, ia.y, ia.z, ia.w, ib.x, ib.y, ib.z, ib.w,
                    ic.x, ic.y, ic.z, ic.w, id.x, id.y, id.z, id.w};
    unsigned short gg[16];
#pragma unroll
    for (int j = 0; j < 16; ++j) gg[j] = h2b[(unsigned)idxs[j] * 40u + lc];
    float t0 = pv0 + sdv; t0 = fmaxf(t0, 0.2f * t0); float w0 = __expf(t0);
    float t1 = pv1 + sdv; t1 = fmaxf(t1, 0.2f * t1); float w1 = __expf(t1);
    z += w0 + w1;
#pragma unroll
    for (int j = 0; j < 8; ++j) {
      float wj = __shfl(w0, j * 8, 64);
      acc = fmaf(wj, bf2f(gg[j]), acc);
    }
#pragma unroll
    for (int j = 0; j < 8; ++j) {
      float wj = __shfl(w1, j * 8, 64);
      acc2 = fmaf(wj, bf2f(gg[8 + j]), acc2);
    }
  }
  acc += acc2;
  z += __shfl_xor(z, 8); z += __shfl_xor(z, 16); z += __shfl_xor(z, 32);  // all lanes: Z
  float v = act ? (acc / (z + 1e-16f) + b2[l]) : -1e30f;
  float m = v;
  for (int off = 32; off > 0; off >>= 1) m = fmaxf(m, __shfl_xor(m, off));
  float ex = act ? __expf(v - m) : 0.f;
  float s = ex;
  for (int off = 32; off > 0; off >>= 1) s += __shfl_xor(s, off);
  if (act) out[(size_t)n * 40 + l] = v - m - logf(s);
}

// ---------------- launch -----------------------------------------------------
extern "C" void kernel_launch(void* const* d_in, const int* in_sizes, int n_in,
                              void* d_out, int out_size, void* d_ws, size_t ws_size,
                              hipStream_t stream) {
  const float* x   = (const float*)d_in[0];
  const int*   ei  = (const int*)d_in[1];
  const float* W1  = (const float*)d_in[2];
  const float* a1s = (const float*)d_in[3];
  const float* a1d = (const float*)d_in[4];
  const float* b1  = (const float*)d_in[5];
  const float* W2  = (const float*)d_in[6];
  const float* a2s = (const float*)d_in[7];
  const float* a2d = (const float*)d_in[8];
  const float* b2  = (const float*)d_in[9];
  float* out = (float*)d_out;
  (void)n_in; (void)out_size; (void)ws_size;

  const int NN = in_sizes[0] / 256;
  const int E  = in_sizes[1] / 2;
  const int NB = (NN + KNODES - 1) >> BK;
  const int* esrc = ei;
  const int* edst = ei + E;

  // fixed per-bucket payload capacity: mean + 31% + 512 (>>30 sigma for iid edges)
  int capP = (E + NB - 1) / NB;
  capP += capP / 4 + capP / 16 + 512;
  capP = (capP + 15) & ~15;

  char* p = (char*)d_ws;
  auto alloc = [&](size_t bytes) -> char* {
    char* q = p;
    p += (bytes + 255) & ~(size_t)255;
    return q;
  };
  unsigned short* h1b   = (unsigned short*)alloc((size_t)(NN + 1) * 64 * 2);
  unsigned short* helub = (unsigned short*)alloc((size_t)NN * 64 * 2);
  unsigned short* h2b   = (unsigned short*)alloc((size_t)(NN + 1) * 40 * 2);
  float* s1s  = (float*)alloc((size_t)(NN + 1) * 8 * 4);
  float* s1d  = (float*)alloc((size_t)NN * 8 * 4);
  float* s2s  = (float*)alloc((size_t)(NN + 1) * 4);
  float* s2d  = (float*)alloc((size_t)NN * 4);
  int*   rbeg = (int*)alloc((size_t)NN * 4);
  int*   rend = (int*)alloc((size_t)NN * 4);
  int*   bpos = (int*)alloc(MAXNB * 4);
  unsigned int* payload = (unsigned int*)alloc((size_t)NB * capP * 4);
  int*   col  = (int*)alloc((size_t)NB * (capP + 8 * KNODES) * 4);
  float* vas  = (float*)alloc(64 * 4);
  float* vad  = (float*)alloc(64 * 4);
  unsigned short* w1hi = (unsigned short*)alloc(32 * 64 * 8 * 2);
  unsigned short* w1lo = (unsigned short*)alloc(32 * 64 * 8 * 2);
  unsigned short* w2hi = (unsigned short*)alloc(6 * 64 * 8 * 2);
  unsigned short* w2lo = (unsigned short*)alloc(6 * 64 * 8 * 2);

  // 1) prep (bpos init, W1/W2 frags, va, sentinels)
  prep_kernel<<<40, 256, 0, stream>>>(W1, W2, a2s, a2d, w1hi, w1lo, w2hi, w2lo,
                                      vas, vad, h1b, h2b, s1s, s2s, bpos, capP, NN);
  // 2-3) CSR build
  bin_kernel<<<(E + 4095) / 4096, 256, 0, stream>>>(esrc, edst, bpos, payload, E, NB, capP);
  fill2_kernel<<<NB, 1024, 0, stream>>>(payload, bpos, col, rbeg, rend, capP, NN);
  // 4-7) dense math + aggregations (s1 fused into gemm1)
  gemm1_mfma_kernel<<<(NN + 63) / 64, 256, 0, stream>>>(x, w1hi, w1lo, a1s, a1d,
                                                        h1b, s1s, s1d, NN);
  agg1_kernel<<<(NN + 3) / 4, 256, 0, stream>>>(rbeg, rend, col, s1s, s1d, h1b, b1,
                                                vas, vad, helub, s2s, s2d, NN);
  gemm2_mfma_kernel<<<(NN + 63) / 64, 256, 0, stream>>>(helub, w2hi, w2lo, h2b, NN);
  agg2_kernel<<<(NN + 3) / 4, 256, 0, stream>>>(rbeg, rend, col, s2s, s2d, h2b, b2, out, NN);
}

// Round 6
// 337.299 us; speedup vs baseline: 1.0577x; 1.0479x over previous
//
#include <hip/hip_runtime.h>
#include <math.h>

#define BK 10
#define KNODES 1024   // nodes per bucket
#define MAXNB 128     // max buckets (N <= 131072, src fits 17 bits)

typedef __attribute__((ext_vector_type(8))) short bf16x8;
typedef __attribute__((ext_vector_type(4))) float f32x4;

// ---- bf16 helpers ----------------------------------------------------------
__device__ __forceinline__ float bf2f(unsigned short u) {
  return __uint_as_float(((unsigned int)u) << 16);
}
__device__ __forceinline__ unsigned short f2bf(float f) {
  unsigned int i = __float_as_uint(f);
  unsigned int r = i + 0x7FFFu + ((i >> 16) & 1u);   // round-to-nearest-even
  return (unsigned short)(r >> 16);
}

// ---------------- prep: bpos init + W1/W2 frags + va + sentinels (1 launch) --
__global__ __launch_bounds__(256) void prep_kernel(
    const float* __restrict__ W1, const float* __restrict__ W2,
    const float* __restrict__ a2s, const float* __restrict__ a2d,
    unsigned short* __restrict__ whi, unsigned short* __restrict__ wlo,
    unsigned short* __restrict__ w2hi, unsigned short* __restrict__ w2lo,
    float* __restrict__ vas, float* __restrict__ vad,
    unsigned short* __restrict__ h1b, unsigned short* __restrict__ h2b,
    float* __restrict__ s1s, float* __restrict__ s2s,
    int* __restrict__ bpos, int capP, int NN) {
  const int blk = blockIdx.x, t = threadIdx.x;
  if (blk == 0 && t < MAXNB) bpos[t] = t * capP;
  if (blk < 32) {
    if (t < 64) {
      // W1 -> MFMA B-frag layout, hi/lo bf16 split. tile b=kt*4+ct
      int b = blk, lane = t;
      int kt = b >> 2, ct = b & 3;
      int n = lane & 15, g = lane >> 4;
      unsigned short hb[8], lb[8];
#pragma unroll
      for (int j = 0; j < 8; ++j) {
        int k = kt * 32 + g * 8 + j;
        float wv = W1[k * 64 + ct * 16 + n];
        unsigned short hi = f2bf(wv);
        float rem = wv - bf2f(hi);
        hb[j] = hi;
        lb[j] = f2bf(rem);
      }
      size_t base = ((size_t)b * 64 + lane) * 8;
      *(ushort4*)(whi + base)     = make_ushort4(hb[0], hb[1], hb[2], hb[3]);
      *(ushort4*)(whi + base + 4) = make_ushort4(hb[4], hb[5], hb[6], hb[7]);
      *(ushort4*)(wlo + base)     = make_ushort4(lb[0], lb[1], lb[2], lb[3]);
      *(ushort4*)(wlo + base + 4) = make_ushort4(lb[4], lb[5], lb[6], lb[7]);
    }
  } else if (blk == 32) {
    if (t < 64) {
      float s = 0.f, d = 0.f;
      for (int c = 0; c < 40; ++c) {
        float w = W2[t * 40 + c];
        s += w * a2s[c];
        d += w * a2d[c];
      }
      vas[t] = s;
      vad[t] = d;
    }
  } else if (blk == 33) {
    if (t < 64) {
      h1b[(size_t)NN * 64 + t] = 0;
      if (t < 40) h2b[(size_t)NN * 40 + t] = 0;
      if (t < 8)  s1s[(size_t)NN * 8 + t] = -1e30f;
      if (t == 0) s2s[NN] = -1e30f;
    }
  } else if (blk >= 34 && blk < 40) {
    if (t < 64) {
      // W2 -> MFMA B-frag layout, hi/lo bf16 split. tile b = kt*3+ct (kt<2, ct<3)
      int b = blk - 34;
      int kt = b / 3, ct = b % 3;
      int n = t & 15, g = t >> 4;
      unsigned short hb[8], lb[8];
#pragma unroll
      for (int j = 0; j < 8; ++j) {
        int k = kt * 32 + g * 8 + j;          // < 64
        int c = ct * 16 + n;
        float wv = (c < 40) ? W2[k * 40 + c] : 0.f;
        unsigned short hi = f2bf(wv);
        float rem = wv - bf2f(hi);
        hb[j] = hi;
        lb[j] = f2bf(rem);
      }
      size_t base = ((size_t)b * 64 + t) * 8;
      *(ushort4*)(w2hi + base)     = make_ushort4(hb[0], hb[1], hb[2], hb[3]);
      *(ushort4*)(w2hi + base + 4) = make_ushort4(hb[4], hb[5], hb[6], hb[7]);
      *(ushort4*)(w2lo + base)     = make_ushort4(lb[0], lb[1], lb[2], lb[3]);
      *(ushort4*)(w2lo + base + 4) = make_ushort4(lb[4], lb[5], lb[6], lb[7]);
    }
  }
}

// ---------------- fused GEMM1(+s1) / bin kernel ------------------------------
// gemm1 blocks: round-2 proven structure (LDS DMA staging, XOR-swizzled global
// source, per-half drain). bin blocks interleaved among them fill gemm1's
// memory-stall bubbles (both depend only on prep; independent of each other).
__global__ __launch_bounds__(256) void g1bin_kernel(
    const float* __restrict__ x, const unsigned short* __restrict__ whi,
    const unsigned short* __restrict__ wlo,
    const float* __restrict__ a_src, const float* __restrict__ a_dst,
    unsigned short* __restrict__ h1b,
    float* __restrict__ s_src, float* __restrict__ s_dst, int N,
    const int* __restrict__ esrc, const int* __restrict__ edst,
    int* __restrict__ bpos, unsigned int* __restrict__ payload,
    int E, int NB, int capP, int nG1, int nBin) {
  __shared__ union {
    float xtile[4][2048];   // gemm1: per wave 16 rows x 128 floats (half-K) = 8KB
    struct {
      int hist[MAXNB], soff[MAXNB], base[MAXNB], rnk[MAXNB];
      unsigned int stage[4096];
    } b;                    // bin: 18 KB
  } sm;

  const int bid = blockIdx.x;
  int isBin, id;
  if (2 * nBin <= nG1 + nBin) {     // interleave bin among first 2*nBin blocks
    if (bid < 2 * nBin) { isBin = bid & 1; id = bid >> 1; }
    else                { isBin = 0;       id = bid - nBin; }
  } else {                          // fallback: bin first
    isBin = (bid < nBin);
    id = isBin ? bid : bid - nBin;
  }

  if (isBin) {
    // ---------------- bin body (verbatim, blockIdx -> id) ----------------
    const int t = threadIdx.x;
    const int e0 = id * 4096;
    if (t < MAXNB) { sm.b.hist[t] = 0; sm.b.rnk[t] = 0; }
    __syncthreads();
    for (int j = t; j < 4096; j += 256) {
      int e = e0 + j;
      if (e < E) atomicAdd(&sm.b.hist[edst[e] >> BK], 1);
    }
    __syncthreads();
    if (t == 0) {
      int acc = 0;
      for (int b = 0; b < NB; ++b) { sm.b.soff[b] = acc; acc += sm.b.hist[b]; }
    }
    __syncthreads();
    if (t < NB) {
      int c = sm.b.hist[t];
      sm.b.base[t] = c ? atomicAdd(&bpos[t], c) : 0;
    }
    __syncthreads();
    for (int j = t; j < 4096; j += 256) {
      int e = e0 + j;
      if (e < E) {
        int d = edst[e];
        int b = d >> BK;
        int s = esrc[e];
        int r = atomicAdd(&sm.b.rnk[b], 1);
        sm.b.stage[sm.b.soff[b] + r] =
            (((unsigned)(d & (KNODES - 1))) << 17) | (unsigned)s;
      }
    }
    __syncthreads();
    int wave = t >> 6, lane = t & 63;
    for (int b = wave; b < NB; b += 4) {
      int len = sm.b.hist[b], bs = sm.b.soff[b], gb = sm.b.base[b];
      int lim = (b + 1) * capP;
      for (int j = lane; j < len; j += 64)
        if (gb + j < lim) payload[gb + j] = sm.b.stage[bs + j];   // overflow guard
    }
    return;
  }

  // ---------------- gemm1 body (round-2 proven version, blockIdx -> id) -----
  const int w = threadIdx.x >> 6, lane = threadIdx.x & 63;
  const int m = lane & 15, g = lane >> 4;
  const int rbase = id * 64 + w * 16;
  float* xw = sm.xtile[w];

  const int lrow2 = lane >> 5;       // which of the 2 rows this lane loads
  const int lch   = lane & 31;       // 16B-chunk index within 512B half-row
  const int msw   = m & 7;           // read-side swizzle key

  f32x4 acc[4] = {{0.f, 0.f, 0.f, 0.f}, {0.f, 0.f, 0.f, 0.f},
                  {0.f, 0.f, 0.f, 0.f}, {0.f, 0.f, 0.f, 0.f}};

#pragma unroll
  for (int half = 0; half < 2; ++half) {
    const int colbase = half * 128;  // float offset of this half-K within a row
    if (half) asm volatile("s_waitcnt lgkmcnt(0)" ::: "memory");  // LDS reuse guard
#pragma unroll
    for (int j = 0; j < 8; ++j) {
      int lrow = 2 * j + lrow2;                 // local row 0..15
      int row = rbase + lrow;
      if (row >= N) row = N - 1;                // clamp: garbage rows never stored
      int sw = lrow & 7;                        // source pre-swizzle (involution)
      const float* src = x + (size_t)row * 256 + colbase + ((lch ^ sw) << 2);
      __builtin_amdgcn_global_load_lds(
          (const __attribute__((address_space(1))) unsigned int*)src,
          (__attribute__((address_space(3))) unsigned int*)(xw + j * 256),
          16, 0, 0);
    }
    asm volatile("s_waitcnt vmcnt(0)" ::: "memory");
#pragma unroll
    for (int ktl = 0; ktl < 4; ++ktl) {
      const int kt = half * 4 + ktl;
      const int c0 = ktl * 8 + g * 2;           // 16B-chunk pair for (m,g)
      const float* p0 = xw + m * 128 + (((c0)     ^ msw) << 2);
      const float* p1 = xw + m * 128 + (((c0 + 1) ^ msw) << 2);
      float4 a0 = *(const float4*)p0;
      float4 a1 = *(const float4*)p1;
      float av[8] = {a0.x, a0.y, a0.z, a0.w, a1.x, a1.y, a1.z, a1.w};
      bf16x8 ahi, alo;
#pragma unroll
      for (int j = 0; j < 8; ++j) {
        unsigned int u = __float_as_uint(av[j]);
        unsigned short hi = (unsigned short)(u >> 16);      // truncate
        float rem = av[j] - bf2f(hi);
        ahi[j] = (short)hi;
        alo[j] = (short)(__float_as_uint(rem) >> 16);       // truncate residual
      }
      const unsigned short* wp = whi + ((size_t)(kt * 4) * 64 + lane) * 8;
      const unsigned short* lp = wlo + ((size_t)(kt * 4) * 64 + lane) * 8;
#pragma unroll
      for (int ct = 0; ct < 4; ++ct) {
        bf16x8 bh = *(const bf16x8*)(wp + (size_t)ct * 64 * 8);
        bf16x8 bl = *(const bf16x8*)(lp + (size_t)ct * 64 * 8);
        acc[ct] = __builtin_amdgcn_mfma_f32_16x16x32_bf16(ahi, bh, acc[ct], 0, 0, 0);
        acc[ct] = __builtin_amdgcn_mfma_f32_16x16x32_bf16(alo, bh, acc[ct], 0, 0, 0);
        acc[ct] = __builtin_amdgcn_mfma_f32_16x16x32_bf16(ahi, bl, acc[ct], 0, 0, 0);
      }
    }
  }
  // ---- h1b stores ----
#pragma unroll
  for (int r = 0; r < 4; ++r) {
    int ro = rbase + g * 4 + r;
    if (ro < N) {
#pragma unroll
      for (int ct = 0; ct < 4; ++ct)
        h1b[(size_t)ro * 64 + ct * 16 + m] = f2bf(acc[ct][r]);
    }
  }
  // ---- fused s1: head h = ct*2 + (m>>3); its 8 dims live on the m&7 group ----
  float a1sv[4], a1dv[4];
#pragma unroll
  for (int ct = 0; ct < 4; ++ct) {
    a1sv[ct] = a_src[ct * 16 + m];
    a1dv[ct] = a_dst[ct * 16 + m];
  }
#pragma unroll
  for (int r = 0; r < 4; ++r) {
    float ps[4], pd[4];
#pragma unroll
    for (int ct = 0; ct < 4; ++ct) {
      ps[ct] = acc[ct][r] * a1sv[ct];
      pd[ct] = acc[ct][r] * a1dv[ct];
    }
#pragma unroll
    for (int off = 1; off < 8; off <<= 1) {
#pragma unroll
      for (int ct = 0; ct < 4; ++ct) {
        ps[ct] += __shfl_xor(ps[ct], off);
        pd[ct] += __shfl_xor(pd[ct], off);
      }
    }
    int ro = rbase + g * 4 + r;
    if ((m & 7) == 0 && ro < N) {
      int hb2 = m >> 3;       // 0 or 1
#pragma unroll
      for (int ct = 0; ct < 4; ++ct) {
        s_src[(size_t)ro * 8 + ct * 2 + hb2] = ps[ct];
        s_dst[(size_t)ro * 8 + ct * 2 + hb2] = pd[ct];
      }
    }
  }
}

// ---------------- fill2: count + wave-shfl padded scan + scatter + pad -------
__global__ __launch_bounds__(1024) void fill2_kernel(const unsigned int* __restrict__ payload,
                                                     const int* __restrict__ bpos,
                                                     int* __restrict__ col,
                                                     int* __restrict__ rbeg,
                                                     int* __restrict__ rend,
                                                     int capP, int NN) {
  __shared__ int cnt[KNODES], pos[KNODES];
  __shared__ int wsum[16];
  const int b = blockIdx.x, t = threadIdx.x;
  cnt[t] = 0;
  __syncthreads();
  const int beg = b * capP;
  int len = bpos[b] - beg;
  if (len > capP) len = capP;
  for (int j = t; j < len; j += 1024) atomicAdd(&cnt[payload[beg + j] >> 17], 1);
  __syncthreads();
  const int myc = cnt[t];
  const int padc = (myc + 7) & ~7;
  const int lane = t & 63, wid = t >> 6;
  // wave-level inclusive scan of padc
  int v = padc;
#pragma unroll
  for (int off = 1; off < 64; off <<= 1) {
    int u = __shfl_up(v, off, 64);
    if (lane >= off) v += u;
  }
  if (lane == 63) wsum[wid] = v;
  __syncthreads();
  if (t < 16) {
    int sv = wsum[t];
#pragma unroll
    for (int off = 1; off < 16; off <<= 1) {
      int u = __shfl_up(sv, off, 64);
      if ((int)t >= off) sv += u;
    }
    wsum[t] = sv;
  }
  __syncthreads();
  const int incl = v + (wid ? wsum[wid - 1] : 0);               // inclusive scan
  const int mystart = b * (capP + 8 * KNODES) + incl - padc;    // exclusive
  const int n = (b << BK) + t;
  if (n < NN) { rbeg[n] = mystart; rend[n] = mystart + padc; }
  pos[t] = mystart;
  __syncthreads();
  for (int j = t; j < len; j += 1024) {
    unsigned int pay = payload[beg + j];
    int p = atomicAdd(&pos[pay >> 17], 1);
    col[p] = (int)(pay & 0x1FFFF);
  }
  __syncthreads();
  // sentinel-pad each row to padc (<=7 writes per node)
  for (int j = mystart + myc; j < mystart + padc; ++j) col[j] = NN;
}

// ---------------- layer-1 aggregation + fused GEMM2 tail ---------------------
// 512 threads = 8 nodes/block. Each wave computes its node's v (as before),
// stores f32 v into LDS; wave 0 then runs the 16x16x32 MFMA gemm2 on f2bf(v)
// -- bit-identical to the old helub->gemm2 path, helub eliminated.
__global__ __launch_bounds__(512) void agg1_kernel(
    const int* __restrict__ rbeg, const int* __restrict__ rend,
    const int* __restrict__ col,
    const float* __restrict__ s_src, const float* __restrict__ s_dst,
    const unsigned short* __restrict__ h1b, const float* __restrict__ b1,
    const float* __restrict__ vas, const float* __restrict__ vad,
    const unsigned short* __restrict__ w2hi, const unsigned short* __restrict__ w2lo,
    unsigned short* __restrict__ h2b, float* __restrict__ s2s,
    float* __restrict__ s2d, int N) {
  __shared__ float vsh[16][68];   // 8 used rows; 68-pad -> 2-way banks (free)
  const int t  = threadIdx.x;
  const int wv = t >> 6;
  const int l  = t & 63;
  const int n  = blockIdx.x * 8 + wv;
  const bool alive = (n < N);
  float v = 0.f;
  if (alive) {
    const int q  = l >> 3;          // edge slot for score stream
    const int hh = l & 7;           // head for score stream
    const float sdq = s_dst[n * 8 + hh];
    const int beg = __builtin_amdgcn_readfirstlane(rbeg[n]);
    const int end = __builtin_amdgcn_readfirstlane(rend[n]);
    float z = 0.f, acc = 0.f, acc2 = 0.f;
    int e = beg;
    if (((end - beg) >> 3) & 1) {   // odd 8-block first (wave-uniform branch)
      int4 ia = *(const int4*)(col + e);
      int4 ib = *(const int4*)(col + e + 4);
      int myidx = col[e + q];
      float pv = s_src[(unsigned)myidx * 8u + (unsigned)hh];
      float tt = pv + sdq;
      tt = fmaxf(tt, 0.2f * tt);
      float ww = __expf(tt);
      z += ww;
      int idxs[8] = {ia.x, ia.y, ia.z, ia.w, ib.x, ib.y, ib.z, ib.w};
#pragma unroll
      for (int j = 0; j < 8; ++j) {
        float wj = __shfl(ww, j * 8 + q, 64);
        unsigned short gbit = h1b[(unsigned)idxs[j] * 64u + (unsigned)l];
        acc = fmaf(wj, bf2f(gbit), acc);
      }
      e += 8;
    }
    for (; e < end; e += 16) {
      int4 ia = *(const int4*)(col + e);
      int4 ib = *(const int4*)(col + e + 4);
      int4 ic = *(const int4*)(col + e + 8);
      int4 id = *(const int4*)(col + e + 12);
      int my0 = col[e + q];
      int my1 = col[e + 8 + q];
      float pv0 = s_src[(unsigned)my0 * 8u + (unsigned)hh];
      float pv1 = s_src[(unsigned)my1 * 8u + (unsigned)hh];
      int idxs[16] = {ia.x, ia.y, ia.z, ia.w, ib.x, ib.y, ib.z, ib.w,
                      ic.x, ic.y, ic.z, ic.w, id.x, id.y, id.z, id.w};
      unsigned short gg[16];
#pragma unroll
      for (int j = 0; j < 16; ++j) gg[j] = h1b[(unsigned)idxs[j] * 64u + (unsigned)l];
      float t0 = pv0 + sdq; t0 = fmaxf(t0, 0.2f * t0); float w0 = __expf(t0);
      float t1 = pv1 + sdq; t1 = fmaxf(t1, 0.2f * t1); float w1 = __expf(t1);
      z += w0 + w1;
#pragma unroll
      for (int j = 0; j < 8; ++j) {
        float wj = __shfl(w0, j * 8 + q, 64);
        acc = fmaf(wj, bf2f(gg[j]), acc);
      }
#pragma unroll
      for (int j = 0; j < 8; ++j) {
        float wj = __shfl(w1, j * 8 + q, 64);
        acc2 = fmaf(wj, bf2f(gg[8 + j]), acc2);
      }
    }
    acc += acc2;
    z += __shfl_xor(z, 8); z += __shfl_xor(z, 16); z += __shfl_xor(z, 32);
    float zf = __shfl(z, 9 * q, 64);
    v = acc / (zf + 1e-16f) + b1[l];
    v = v > 0.f ? v : (__expf(v) - 1.f);       // elu
    float ps = v * vas[l];
    float pd = v * vad[l];
    for (int off = 32; off > 0; off >>= 1) {
      ps += __shfl_xor(ps, off);
      pd += __shfl_xor(pd, off);
    }
    if (l == 0) { s2s[n] = ps; s2d[n] = pd; }
  }
  vsh[wv][l] = v;
  __syncthreads();
  // ---- GEMM2 tail on wave 0: h2b[8 nodes][40] = f2bf(vsh) @ W2 (hi/lo) ----
  if (wv == 0) {
    const int m = l & 15, g = l >> 4;
    const int rbase2 = blockIdx.x * 8;
    f32x4 acc2t[3] = {{0.f, 0.f, 0.f, 0.f}, {0.f, 0.f, 0.f, 0.f},
                      {0.f, 0.f, 0.f, 0.f}};
#pragma unroll
    for (int kt = 0; kt < 2; ++kt) {
      bf16x8 a;
#pragma unroll
      for (int j = 0; j < 8; ++j)
        a[j] = (short)f2bf(vsh[m][kt * 32 + g * 8 + j]);  // m>=8 rows unused
#pragma unroll
      for (int ct = 0; ct < 3; ++ct) {
        int b = kt * 3 + ct;
        bf16x8 bh = *(const bf16x8*)(w2hi + ((size_t)b * 64 + l) * 8);
        bf16x8 bl = *(const bf16x8*)(w2lo + ((size_t)b * 64 + l) * 8);
        acc2t[ct] = __builtin_amdgcn_mfma_f32_16x16x32_bf16(a, bh, acc2t[ct], 0, 0, 0);
        acc2t[ct] = __builtin_amdgcn_mfma_f32_16x16x32_bf16(a, bl, acc2t[ct], 0, 0, 0);
      }
    }
#pragma unroll
    for (int r = 0; r < 4; ++r) {
      int row = g * 4 + r;
      int ro  = rbase2 + row;
      if (row < 8 && ro < N) {     // only this block's 8 nodes
#pragma unroll
        for (int ct = 0; ct < 3; ++ct) {
          int c = ct * 16 + m;
          if (c < 40) h2b[(size_t)ro * 40 + c] = f2bf(acc2t[ct][r]);
        }
      }
    }
  }
}

// ---------------- layer-2 aggregation + log_softmax (16-deep) ----------------
__global__ __launch_bounds__(256) void agg2_kernel(
    const int* __restrict__ rbeg, const int* __restrict__ rend,
    const int* __restrict__ col,
    const float* __restrict__ s2s, const float* __restrict__ s2d,
    const unsigned short* __restrict__ h2b, const float* __restrict__ b2,
    float* __restrict__ out, int N) {
  int wv = threadIdx.x >> 6;
  int l  = threadIdx.x & 63;
  int n  = blockIdx.x * 4 + wv;
  if (n >= N) return;
  const int q = l >> 3;
  const bool act = (l < 40);
  const unsigned lc = act ? (unsigned)l : 0u;
  const float sdv = s2d[n];
  const int beg = __builtin_amdgcn_readfirstlane(rbeg[n]);
  const int end = __builtin_amdgcn_readfirstlane(rend[n]);
  float z = 0.f, acc = 0.f, acc2 = 0.f;
  int e = beg;
  if (((end - beg) >> 3) & 1) {
    int4 ia = *(const int4*)(col + e);
    int4 ib = *(const int4*)(col + e + 4);
    int myidx = col[e + q];
    float pv = s2s[myidx];
    float tt = pv + sdv;
    tt = fmaxf(tt, 0.2f * tt);
    float w = __expf(tt);
    z += w;
    int idxs[8] = {ia.x, ia.y, ia.z, ia.w, ib.x, ib.y, ib.z, ib.w};
#pragma unroll
    for (int j = 0; j < 8; ++j) {
      float wj = __shfl(w, j * 8, 64);
      unsigned short g = h2b[(unsigned)idxs[j] * 40u + lc];
      acc = fmaf(wj, bf2f(g), acc);
    }
    e += 8;
  }
  for (; e < end; e += 16) {
    int4 ia = *(const int4*)(col + e);
    int4 ib = *(const int4*)(col + e + 4);
    int4 ic = *(const int4*)(col + e + 8);
    int4 id = *(const int4*)(col + e + 12);
    int my0 = col[e + q];
    int my1 = col[e + 8 + q];
    float pv0 = s2s[my0];
    float pv1 = s2s[my1];
    int idxs[16] = {ia.x, ia.y, ia.z, ia.w, ib.x, ib.y, ib.z, ib.w,
                    ic.x, ic.y, ic.z, ic.w, id.x, id.y, id.z, id.w};
    unsigned short gg[16];
#pragma unroll
    for (int j = 0; j < 16; ++j) gg[j] = h2b[(unsigned)idxs[j] * 40u + lc];
    float t0 = pv0 + sdv; t0 = fmaxf(t0, 0.2f * t0); float w0 = __expf(t0);
    float t1 = pv1 + sdv; t1 = fmaxf(t1, 0.2f * t1); float w1 = __expf(t1);
    z += w0 + w1;
#pragma unroll
    for (int j = 0; j < 8; ++j) {
      float wj = __shfl(w0, j * 8, 64);
      acc = fmaf(wj, bf2f(gg[j]), acc);
    }
#pragma unroll
    for (int j = 0; j < 8; ++j) {
      float wj = __shfl(w1, j * 8, 64);
      acc2 = fmaf(wj, bf2f(gg[8 + j]), acc2);
    }
  }
  acc += acc2;
  z += __shfl_xor(z, 8); z += __shfl_xor(z, 16); z += __shfl_xor(z, 32);  // all lanes: Z
  float v = act ? (acc / (z + 1e-16f) + b2[l]) : -1e30f;
  float m = v;
  for (int off = 32; off > 0; off >>= 1) m = fmaxf(m, __shfl_xor(m, off));
  float ex = act ? __expf(v - m) : 0.f;
  float s = ex;
  for (int off = 32; off > 0; off >>= 1) s += __shfl_xor(s, off);
  if (act) out[(size_t)n * 40 + l] = v - m - logf(s);
}

// ---------------- launch -----------------------------------------------------
extern "C" void kernel_launch(void* const* d_in, const int* in_sizes, int n_in,
                              void* d_out, int out_size, void* d_ws, size_t ws_size,
                              hipStream_t stream) {
  const float* x   = (const float*)d_in[0];
  const int*   ei  = (const int*)d_in[1];
  const float* W1  = (const float*)d_in[2];
  const float* a1s = (const float*)d_in[3];
  const float* a1d = (const float*)d_in[4];
  const float* b1  = (const float*)d_in[5];
  const float* W2  = (const float*)d_in[6];
  const float* a2s = (const float*)d_in[7];
  const float* a2d = (const float*)d_in[8];
  const float* b2  = (const float*)d_in[9];
  float* out = (float*)d_out;
  (void)n_in; (void)out_size; (void)ws_size;

  const int NN = in_sizes[0] / 256;
  const int E  = in_sizes[1] / 2;
  const int NB = (NN + KNODES - 1) >> BK;
  const int* esrc = ei;
  const int* edst = ei + E;

  // fixed per-bucket payload capacity: mean + 31% + 512 (>>30 sigma for iid edges)
  int capP = (E + NB - 1) / NB;
  capP += capP / 4 + capP / 16 + 512;
  capP = (capP + 15) & ~15;

  char* p = (char*)d_ws;
  auto alloc = [&](size_t bytes) -> char* {
    char* q = p;
    p += (bytes + 255) & ~(size_t)255;
    return q;
  };
  unsigned short* h1b   = (unsigned short*)alloc((size_t)(NN + 1) * 64 * 2);
  unsigned short* h2b   = (unsigned short*)alloc((size_t)(NN + 1) * 40 * 2);
  float* s1s  = (float*)alloc((size_t)(NN + 1) * 8 * 4);
  float* s1d  = (float*)alloc((size_t)NN * 8 * 4);
  float* s2s  = (float*)alloc((size_t)(NN + 1) * 4);
  float* s2d  = (float*)alloc((size_t)NN * 4);
  int*   rbeg = (int*)alloc((size_t)NN * 4);
  int*   rend = (int*)alloc((size_t)NN * 4);
  int*   bpos = (int*)alloc(MAXNB * 4);
  unsigned int* payload = (unsigned int*)alloc((size_t)NB * capP * 4);
  int*   col  = (int*)alloc((size_t)NB * (capP + 8 * KNODES) * 4);
  float* vas  = (float*)alloc(64 * 4);
  float* vad  = (float*)alloc(64 * 4);
  unsigned short* w1hi = (unsigned short*)alloc(32 * 64 * 8 * 2);
  unsigned short* w1lo = (unsigned short*)alloc(32 * 64 * 8 * 2);
  unsigned short* w2hi = (unsigned short*)alloc(6 * 64 * 8 * 2);
  unsigned short* w2lo = (unsigned short*)alloc(6 * 64 * 8 * 2);

  const int nG1  = (NN + 63) / 64;
  const int nBin = (E + 4095) / 4096;

  // 1) prep (bpos init, W1/W2 frags, va, sentinels)
  prep_kernel<<<40, 256, 0, stream>>>(W1, W2, a2s, a2d, w1hi, w1lo, w2hi, w2lo,
                                      vas, vad, h1b, h2b, s1s, s2s, bpos, capP, NN);
  // 2) fused gemm1(+s1) and bin (independent; bin fills gemm1 stall bubbles)
  g1bin_kernel<<<nG1 + nBin, 256, 0, stream>>>(x, w1hi, w1lo, a1s, a1d, h1b,
                                               s1s, s1d, NN, esrc, edst, bpos,
                                               payload, E, NB, capP, nG1, nBin);
  // 3) CSR finalize
  fill2_kernel<<<NB, 1024, 0, stream>>>(payload, bpos, col, rbeg, rend, capP, NN);
  // 4) agg1 + fused gemm2 tail (helub eliminated)
  agg1_kernel<<<(NN + 7) / 8, 512, 0, stream>>>(rbeg, rend, col, s1s, s1d, h1b, b1,
                                                vas, vad, w2hi, w2lo, h2b,
                                                s2s, s2d, NN);
  // 5) agg2 + log-softmax
  agg2_kernel<<<(NN + 3) / 4, 256, 0, stream>>>(rbeg, rend, col, s2s, s2d, h2b, b2, out, NN);
}